// Round 1
// baseline (102.786 us; speedup 1.0000x reference)
//
#include <hip/hip_runtime.h>

// RadialNetwork2d: out[b,a] = NORM * sum_k exp(-2*||p_b - c_k||^2) * W[k,a] + bias[a]
// Key insight: centers are a separable 40x40 meshgrid (c_k = (xr[k/40], yr[k%40])),
// and the Gaussian is isotropic, so the basis factorizes:
//   exp(-2*(dx^2+dy^2)) = exp(-2 dx^2) * exp(-2 dy^2)  ->  basis = outer(fx, fy)
// => only 80 exps per row (not 1600), then a 1600x4 FMA contraction:
//   out[a] = NORM * sum_i fx[i] * (sum_j fy[j] * W[i*40+j][a]) + bias[a]
// xr/yr are READ from the centers input (meshgrid 'ij' layout: x at centers[2*(i*40)],
// y at centers[2*j+1]) — no assumption about the grid values themselves.

#define NCX 40
#define NCY 40

__global__ __launch_bounds__(256) void radial_kernel(
    const float2* __restrict__ pos,      // [B] (x,y)
    const float*  __restrict__ centers,  // [1600*2]
    const float4* __restrict__ W,        // [1600] (4 actions)
    const float*  __restrict__ bias,     // [4]
    float4*       __restrict__ out,      // [B]
    int batch)
{
    const int row = blockIdx.x * 256 + threadIdx.x;
    if (row >= batch) return;
    const float2 p = pos[row];

    // fy[j] = exp(-2*(py - yr[j])^2), kept in VGPRs (all indices compile-time const)
    float fy[NCY];
#pragma unroll
    for (int j = 0; j < NCY; ++j) {
        float dy = p.y - centers[2 * j + 1];   // yr[j], wave-uniform address
        fy[j] = __expf(-2.0f * dy * dy);
    }

    float acc0 = 0.f, acc1 = 0.f, acc2 = 0.f, acc3 = 0.f;
    for (int i = 0; i < NCX; ++i) {
        float dx = p.x - centers[2 * (i * NCY)];  // xr[i], wave-uniform address
        float fx = __expf(-2.0f * dx * dx);
        float g0 = 0.f, g1 = 0.f, g2 = 0.f, g3 = 0.f;
#pragma unroll
        for (int j = 0; j < NCY; ++j) {
            const float4 w = W[i * NCY + j];      // wave-uniform -> scalar/L1-broadcast
            const float f = fy[j];
            g0 = fmaf(f, w.x, g0);
            g1 = fmaf(f, w.y, g1);
            g2 = fmaf(f, w.z, g2);
            g3 = fmaf(f, w.w, g3);
        }
        acc0 = fmaf(fx, g0, acc0);
        acc1 = fmaf(fx, g1, acc1);
        acc2 = fmaf(fx, g2, acc2);
        acc3 = fmaf(fx, g3, acc3);
    }

    const float NORMC = 0.6366197723675814f;  // 1/(2*pi*0.25)
    float4 o;
    o.x = fmaf(NORMC, acc0, bias[0]);
    o.y = fmaf(NORMC, acc1, bias[1]);
    o.z = fmaf(NORMC, acc2, bias[2]);
    o.w = fmaf(NORMC, acc3, bias[3]);
    out[row] = o;
}

extern "C" void kernel_launch(void* const* d_in, const int* in_sizes, int n_in,
                              void* d_out, int out_size, void* d_ws, size_t ws_size,
                              hipStream_t stream) {
    const float2* pos     = (const float2*)d_in[0];  // position [B,2]
    const float*  centers = (const float*) d_in[1];  // [1600,2]
    const float4* W       = (const float4*)d_in[2];  // [1600,4]
    const float*  bias    = (const float*) d_in[3];  // [4]
    float4*       out     = (float4*)d_out;          // [B,4]

    const int batch = in_sizes[0] / 2;               // 65536
    const int grid  = (batch + 255) / 256;
    radial_kernel<<<grid, 256, 0, stream>>>(pos, centers, W, bias, out, batch);
}

// Round 2
// 71.955 us; speedup vs baseline: 1.4285x; 1.4285x over previous
//
#include <hip/hip_runtime.h>

// RadialNetwork2d: out[b,a] = NORM * sum_k exp(-2*||p_b - c_k||^2) * W[k,a] + bias[a]
// Centers are a separable 40x40 meshgrid; isotropic Gaussian factorizes:
//   basis = outer(fx, fy), out[a] = NORM * sum_i fx[i] * (sum_j fy[j]*W[i*40+j][a]) + b[a]
//
// R1 -> R2: the R1 kernel (1 thread/row) was latency-bound: 4 waves/CU, VALUBusy 11%.
// Now each 64-row group is handled by one 512-thread block; its 8 waves each take a
// 20x10 tile of the 40x40 center grid (sx in {0,1}, sy in {0..3}), lane = row-in-group.
// 1024 blocks x 8 waves = 32 waves/CU (100% occupancy). Partial sums combined via LDS.
// Tile index goes through readfirstlane so W loads stay wave-uniform -> s_load_dwordx4.

#define NCX 40
#define NCY 40
#define TILE_X 20
#define TILE_Y 10

__global__ __launch_bounds__(512) void radial_kernel(
    const float2* __restrict__ pos,      // [B]
    const float*  __restrict__ centers,  // [1600*2]
    const float4* __restrict__ W,        // [1600]
    const float*  __restrict__ bias,     // [4]
    float*        __restrict__ out,      // [B*4]
    int batch)
{
    const int lane = threadIdx.x & 63;
    // wave id 0..7 — provably uniform via readfirstlane so W indexing scalarizes
    const int wv = __builtin_amdgcn_readfirstlane(threadIdx.x >> 6);
    const int sx = wv & 1;        // x-tile: 2 tiles of 20
    const int sy = wv >> 1;       // y-tile: 4 tiles of 10

    int row = blockIdx.x * 64 + lane;
    if (row >= batch) row = batch - 1;   // clamp (batch is 65536, exact fit)
    const float2 p = pos[row];

    const int j0 = sy * TILE_Y;
    const int i0 = sx * TILE_X;

    // fy[j] for this wave's 10 y-centers (yr[j] = centers[2*j+1], wave-uniform addr)
    float fy[TILE_Y];
#pragma unroll
    for (int j = 0; j < TILE_Y; ++j) {
        float dy = p.y - centers[2 * (j0 + j) + 1];
        fy[j] = __expf(-2.0f * dy * dy);
    }

    float acc0 = 0.f, acc1 = 0.f, acc2 = 0.f, acc3 = 0.f;
#pragma unroll 2
    for (int i = 0; i < TILE_X; ++i) {
        float dx = p.x - centers[2 * ((i0 + i) * NCY)];   // xr[i0+i]
        float fx = __expf(-2.0f * dx * dx);
        float g0 = 0.f, g1 = 0.f, g2 = 0.f, g3 = 0.f;
#pragma unroll
        for (int j = 0; j < TILE_Y; ++j) {
            const float4 w = W[(i0 + i) * NCY + j0 + j];  // uniform -> s_load_dwordx4
            const float f = fy[j];
            g0 = fmaf(f, w.x, g0);
            g1 = fmaf(f, w.y, g1);
            g2 = fmaf(f, w.z, g2);
            g3 = fmaf(f, w.w, g3);
        }
        acc0 = fmaf(fx, g0, acc0);
        acc1 = fmaf(fx, g1, acc1);
        acc2 = fmaf(fx, g2, acc2);
        acc3 = fmaf(fx, g3, acc3);
    }

    // cross-wave reduction: 8 partial sums per (row-in-group, action)
    __shared__ float red[8][64][4];   // 8 KB
    red[wv][lane][0] = acc0;
    red[wv][lane][1] = acc1;
    red[wv][lane][2] = acc2;
    red[wv][lane][3] = acc3;
    __syncthreads();

    if (threadIdx.x < 256) {
        const int t = threadIdx.x;
        const int r = t >> 2;     // row-in-group 0..63
        const int a = t & 3;      // action 0..3
        float s = 0.f;
#pragma unroll
        for (int w = 0; w < 8; ++w) s += red[w][r][a];
        const float NORMC = 0.6366197723675814f;  // 1/(2*pi*0.25)
        const int orow = blockIdx.x * 64 + r;
        if (orow < batch) out[orow * 4 + a] = fmaf(NORMC, s, bias[a]);
    }
}

extern "C" void kernel_launch(void* const* d_in, const int* in_sizes, int n_in,
                              void* d_out, int out_size, void* d_ws, size_t ws_size,
                              hipStream_t stream) {
    const float2* pos     = (const float2*)d_in[0];
    const float*  centers = (const float*) d_in[1];
    const float4* W       = (const float4*)d_in[2];
    const float*  bias    = (const float*) d_in[3];
    float*        out     = (float*)d_out;

    const int batch = in_sizes[0] / 2;          // 65536
    const int grid  = (batch + 63) / 64;        // 1024 blocks of 512 (8 waves)
    radial_kernel<<<grid, 512, 0, stream>>>(pos, centers, W, bias, out, batch);
}

// Round 3
// 69.459 us; speedup vs baseline: 1.4798x; 1.0359x over previous
//
#include <hip/hip_runtime.h>

// RadialNetwork2d: out[b,a] = NORM * sum_k exp(-2*||p_b - c_k||^2) * W[k,a] + bias[a]
// Separable 40x40 meshgrid centers + isotropic Gaussian -> basis = outer(fx, fy):
//   out[a] = NORM * sum_i fx[i] * (sum_j fy[j]*W[i*40+j][a]) + b[a]
//
// R2 -> R3: R2 reached ~16us (est.) vs ~6.8us VALU-issue floor. This round packs the
// 4 per-center FMAs into 2 v_pk_fma_f32 (VOP3P packed fp32) via ext_vector_type(2) +
// __builtin_elementwise_fma, cutting per-thread VALU instrs ~1020 -> ~620. W stays
// wave-uniform (s_load) so pk_fma reads it as an SGPR pair (1 SGPR operand - legal).
// __launch_bounds__(512,8) pins VGPR <= 64 to hold 8 waves/SIMD (occupancy cliff at 64).

#define NCX 40
#define NCY 40
#define TILE_X 20
#define TILE_Y 10

typedef float v2f __attribute__((ext_vector_type(2)));

__global__ __launch_bounds__(512, 8) void radial_kernel(
    const float2* __restrict__ pos,      // [B]
    const float*  __restrict__ centers,  // [1600*2]
    const float4* __restrict__ W,        // [1600]
    const float*  __restrict__ bias,     // [4]
    float*        __restrict__ out,      // [B*4]
    int batch)
{
    const int lane = threadIdx.x & 63;
    const int wv = __builtin_amdgcn_readfirstlane(threadIdx.x >> 6);
    const int sx = wv & 1;        // x-tile: 2 tiles of 20
    const int sy = wv >> 1;       // y-tile: 4 tiles of 10

    int row = blockIdx.x * 64 + lane;
    if (row >= batch) row = batch - 1;
    const float2 p = pos[row];

    const int j0 = sy * TILE_Y;
    const int i0 = sx * TILE_X;

    // fy[j] for this wave's 10 y-centers (wave-uniform center addresses)
    float fy[TILE_Y];
#pragma unroll
    for (int j = 0; j < TILE_Y; ++j) {
        float dy = p.y - centers[2 * (j0 + j) + 1];
        fy[j] = __expf(-2.0f * dy * dy);
    }

    v2f acc01 = {0.f, 0.f}, acc23 = {0.f, 0.f};
#pragma unroll 2
    for (int i = 0; i < TILE_X; ++i) {
        float dx = p.x - centers[2 * ((i0 + i) * NCY)];
        float fx = __expf(-2.0f * dx * dx);
        v2f g01 = {0.f, 0.f}, g23 = {0.f, 0.f};
#pragma unroll
        for (int j = 0; j < TILE_Y; ++j) {
            const float4 w = W[(i0 + i) * NCY + j0 + j];  // uniform -> s_load (SGPRs)
            const v2f w01 = {w.x, w.y};
            const v2f w23 = {w.z, w.w};
            const v2f f2  = {fy[j], fy[j]};
            g01 = __builtin_elementwise_fma(f2, w01, g01);  // v_pk_fma_f32
            g23 = __builtin_elementwise_fma(f2, w23, g23);
        }
        const v2f fx2 = {fx, fx};
        acc01 = __builtin_elementwise_fma(fx2, g01, acc01);
        acc23 = __builtin_elementwise_fma(fx2, g23, acc23);
    }

    // cross-wave reduction: 8 partial sums per (row-in-group, action)
    __shared__ float red[8][64][4];   // 8 KB
    red[wv][lane][0] = acc01.x;
    red[wv][lane][1] = acc01.y;
    red[wv][lane][2] = acc23.x;
    red[wv][lane][3] = acc23.y;
    __syncthreads();

    if (threadIdx.x < 256) {
        const int t = threadIdx.x;
        const int r = t >> 2;     // row-in-group
        const int a = t & 3;      // action
        float s = 0.f;
#pragma unroll
        for (int w = 0; w < 8; ++w) s += red[w][r][a];
        const float NORMC = 0.6366197723675814f;  // 1/(2*pi*0.25)
        const int orow = blockIdx.x * 64 + r;
        if (orow < batch) out[orow * 4 + a] = fmaf(NORMC, s, bias[a]);
    }
}

extern "C" void kernel_launch(void* const* d_in, const int* in_sizes, int n_in,
                              void* d_out, int out_size, void* d_ws, size_t ws_size,
                              hipStream_t stream) {
    const float2* pos     = (const float2*)d_in[0];
    const float*  centers = (const float*) d_in[1];
    const float4* W       = (const float4*)d_in[2];
    const float*  bias    = (const float*) d_in[3];
    float*        out     = (float*)d_out;

    const int batch = in_sizes[0] / 2;          // 65536
    const int grid  = (batch + 63) / 64;        // 1024 blocks x 512 threads (8 waves)
    radial_kernel<<<grid, 512, 0, stream>>>(pos, centers, W, bias, out, batch);
}

// Round 4
// 68.704 us; speedup vs baseline: 1.4961x; 1.0110x over previous
//
#include <hip/hip_runtime.h>

// RadialNetwork2d: out[b,a] = NORM * sum_k exp(-2*||p_b - c_k||^2) * W[k,a] + bias[a]
// Separable 40x40 meshgrid centers + isotropic Gaussian -> basis = outer(fx, fy):
//   out[a] = NORM * sum_i fx[i] * (sum_j fy[j]*W[i*40+j][a]) + b[a]
//
// R3 -> R4: R3 (~13.7us est) was stalling on wave-uniform s_load of W (1 dwordx4 per
// 2 pk_fma). Now each lane handles TWO rows (r0, r0+64): each W float4 feeds 4 pk_fma
// (2x arithmetic intensity per scalar load), total exp work halves, and per-wave ILP
// doubles (4 independent FMA chains). 512 blocks x 512 thr = 16 waves/CU (4/SIMD).

#define NCX 40
#define NCY 40
#define TILE_X 20
#define TILE_Y 10

typedef float v2f __attribute__((ext_vector_type(2)));

__global__ __launch_bounds__(512, 4) void radial_kernel(
    const float2* __restrict__ pos,      // [B]
    const float*  __restrict__ centers,  // [1600*2]
    const float4* __restrict__ W,        // [1600]
    const float*  __restrict__ bias,     // [4]
    float*        __restrict__ out,      // [B*4]
    int batch)
{
    const int lane = threadIdx.x & 63;
    const int wv = __builtin_amdgcn_readfirstlane(threadIdx.x >> 6);
    const int sx = wv & 1;        // x-tile: 2 tiles of 20
    const int sy = wv >> 1;       // y-tile: 4 tiles of 10

    const int base = blockIdx.x * 128;
    int r0 = base + lane;
    int r1 = r0 + 64;
    if (r1 >= batch) r1 = batch - 1;   // batch=65536: exact fit, guards are free
    if (r0 >= batch) r0 = batch - 1;
    const float2 p0 = pos[r0];
    const float2 p1 = pos[r1];

    const int j0 = sy * TILE_Y;
    const int i0 = sx * TILE_X;

    // fy[j] = exp(-2*(py - yr[j])^2) for both rows (yr addresses wave-uniform)
    float fy0[TILE_Y], fy1[TILE_Y];
#pragma unroll
    for (int j = 0; j < TILE_Y; ++j) {
        const float yr = centers[2 * (j0 + j) + 1];
        float d0 = p0.y - yr, d1 = p1.y - yr;
        fy0[j] = __expf(-2.0f * d0 * d0);
        fy1[j] = __expf(-2.0f * d1 * d1);
    }

    v2f a0_01 = {0.f, 0.f}, a0_23 = {0.f, 0.f};
    v2f a1_01 = {0.f, 0.f}, a1_23 = {0.f, 0.f};
#pragma unroll 2
    for (int i = 0; i < TILE_X; ++i) {
        const float xr = centers[2 * ((i0 + i) * NCY)];
        float dx0 = p0.x - xr, dx1 = p1.x - xr;
        float fx0 = __expf(-2.0f * dx0 * dx0);
        float fx1 = __expf(-2.0f * dx1 * dx1);
        v2f g0_01 = {0.f, 0.f}, g0_23 = {0.f, 0.f};
        v2f g1_01 = {0.f, 0.f}, g1_23 = {0.f, 0.f};
#pragma unroll
        for (int j = 0; j < TILE_Y; ++j) {
            const float4 w = W[(i0 + i) * NCY + j0 + j];  // uniform -> s_load (SGPRs)
            const v2f w01 = {w.x, w.y};
            const v2f w23 = {w.z, w.w};
            const v2f f0  = {fy0[j], fy0[j]};
            const v2f f1  = {fy1[j], fy1[j]};
            g0_01 = __builtin_elementwise_fma(f0, w01, g0_01);  // v_pk_fma_f32 x4
            g0_23 = __builtin_elementwise_fma(f0, w23, g0_23);
            g1_01 = __builtin_elementwise_fma(f1, w01, g1_01);
            g1_23 = __builtin_elementwise_fma(f1, w23, g1_23);
        }
        const v2f fx0v = {fx0, fx0};
        const v2f fx1v = {fx1, fx1};
        a0_01 = __builtin_elementwise_fma(fx0v, g0_01, a0_01);
        a0_23 = __builtin_elementwise_fma(fx0v, g0_23, a0_23);
        a1_01 = __builtin_elementwise_fma(fx1v, g1_01, a1_01);
        a1_23 = __builtin_elementwise_fma(fx1v, g1_23, a1_23);
    }

    // cross-wave reduction: 8 partials per (row-in-block 0..127, action)
    __shared__ float red[8][128][4];   // 16 KB
    red[wv][lane][0]      = a0_01.x;
    red[wv][lane][1]      = a0_01.y;
    red[wv][lane][2]      = a0_23.x;
    red[wv][lane][3]      = a0_23.y;
    red[wv][lane + 64][0] = a1_01.x;
    red[wv][lane + 64][1] = a1_01.y;
    red[wv][lane + 64][2] = a1_23.x;
    red[wv][lane + 64][3] = a1_23.y;
    __syncthreads();

    // 512 threads == 128 rows x 4 actions, exactly one output each
    {
        const int t = threadIdx.x;
        const int r = t >> 2;     // row-in-block 0..127
        const int a = t & 3;      // action
        float s = 0.f;
#pragma unroll
        for (int w = 0; w < 8; ++w) s += red[w][r][a];
        const float NORMC = 0.6366197723675814f;  // 1/(2*pi*0.25)
        const int orow = base + r;
        if (orow < batch) out[orow * 4 + a] = fmaf(NORMC, s, bias[a]);
    }
}

extern "C" void kernel_launch(void* const* d_in, const int* in_sizes, int n_in,
                              void* d_out, int out_size, void* d_ws, size_t ws_size,
                              hipStream_t stream) {
    const float2* pos     = (const float2*)d_in[0];
    const float*  centers = (const float*) d_in[1];
    const float4* W       = (const float4*)d_in[2];
    const float*  bias    = (const float*) d_in[3];
    float*        out     = (float*)d_out;

    const int batch = in_sizes[0] / 2;          // 65536
    const int grid  = (batch + 127) / 128;      // 512 blocks x 512 threads (8 waves)
    radial_kernel<<<grid, 512, 0, stream>>>(pos, centers, W, bias, out, batch);
}